// Round 1
// baseline (179.650 us; speedup 1.0000x reference)
//
#include <hip/hip_runtime.h>
#include <math.h>

// Shapes (fixed by harness): B=3200, L=7, H=8, E=64, S=56, D=64, N_STATIONS=50
// queries [B,7,8,64], keys [B,56,8,64], values [B,56,8,64], mask [50,7,56]
// out [B,7,8,64] fp32.
//
// One wave (64 threads) per (b,h) unit. lane = s for scores, lane = d for PV.
// K staged in LDS with stride-68 padding (bank-balanced b128 reads).
// P transposed through LDS (overlaid on K, single-wave in-order DS pipe).

__launch_bounds__(64)
__global__ void fullattn_kernel(const float* __restrict__ q,
                                const float* __restrict__ k,
                                const float* __restrict__ v,
                                const float* __restrict__ mask,
                                float* __restrict__ out,
                                int nstations) {
    __shared__ float Klds[56 * 68];   // padded rows; P overlaid after scores

    const int lane = threadIdx.x;     // 0..63
    const int bid  = blockIdx.x;
    const int b    = bid >> 3;
    const int h    = bid & 7;
    const int st   = b % nstations;

    const int kbase = b * 28672 + h * 64;  // keys/values: b*56*8*64 + h*64
    const int qbase = b * 3584  + h * 64;  // queries/out: b*7*8*64 + h*64

    // ---- stage K -> LDS (padded stride 68), 14 x float4 per lane-chunk ----
#pragma unroll
    for (int it = 0; it < 14; ++it) {
        const int c  = it * 64 + lane;     // chunk 0..895
        const int s  = c >> 4;
        const int e4 = c & 15;
        const float4 val = *(const float4*)(k + kbase + s * 512 + e4 * 4);
        *(float4*)(&Klds[s * 68 + e4 * 4]) = val;
    }

    // ---- mask rows (pre-scaled); clamp pad lanes ----
    const int ml = (lane < 56) ? lane : 55;
    float m[7];
#pragma unroll
    for (int l = 0; l < 7; ++l)
        m[l] = mask[st * 392 + l * 56 + ml] * 0.125f;  // scale = 1/sqrt(64)

    // ---- scores: lane = s, acc[l] = Q[l] . K[s] ----
    const int sc_row = (lane < 56) ? lane : 55;  // clamped LDS row
    float acc[7];
#pragma unroll
    for (int l = 0; l < 7; ++l) acc[l] = 0.0f;

    const float* qp = q + qbase;
#pragma unroll
    for (int e4 = 0; e4 < 16; ++e4) {
        const float4 kv = *(const float4*)(&Klds[sc_row * 68 + e4 * 4]);
#pragma unroll
        for (int l = 0; l < 7; ++l) {
            // wave-uniform address -> scalar (s_load) path
            const float4 q4 = *(const float4*)(qp + l * 512 + e4 * 4);
            acc[l] = fmaf(q4.x, kv.x, acc[l]);
            acc[l] = fmaf(q4.y, kv.y, acc[l]);
            acc[l] = fmaf(q4.z, kv.z, acc[l]);
            acc[l] = fmaf(q4.w, kv.w, acc[l]);
        }
    }

    // ---- softmax across lanes (s), write P to LDS (overlay on dead K) ----
    float* pbuf = Klds;
    float rdenom[7];
#pragma unroll
    for (int l = 0; l < 7; ++l) {
        float sc = acc[l] * m[l];
        if (lane >= 56) sc = -INFINITY;
        float mx = sc;
#pragma unroll
        for (int off = 32; off >= 1; off >>= 1)
            mx = fmaxf(mx, __shfl_xor(mx, off));
        const float p = __expf(sc - mx);   // pad lanes: exp(-inf)=0
        float sum = p;
#pragma unroll
        for (int off = 32; off >= 1; off >>= 1)
            sum += __shfl_xor(sum, off);
        pbuf[l * 64 + lane] = p;
        rdenom[l] = 1.0f / sum;
    }

    // ---- PV: lane = d, V rows streamed straight from global ----
    float facc[7];
#pragma unroll
    for (int l = 0; l < 7; ++l) facc[l] = 0.0f;

#pragma unroll
    for (int s4 = 0; s4 < 14; ++s4) {
        const float vr0 = v[kbase + (s4 * 4 + 0) * 512 + lane];
        const float vr1 = v[kbase + (s4 * 4 + 1) * 512 + lane];
        const float vr2 = v[kbase + (s4 * 4 + 2) * 512 + lane];
        const float vr3 = v[kbase + (s4 * 4 + 3) * 512 + lane];
#pragma unroll
        for (int l = 0; l < 7; ++l) {
            const float4 p4 = *(const float4*)(&pbuf[l * 64 + s4 * 4]);  // broadcast
            facc[l] = fmaf(p4.x, vr0, facc[l]);
            facc[l] = fmaf(p4.y, vr1, facc[l]);
            facc[l] = fmaf(p4.z, vr2, facc[l]);
            facc[l] = fmaf(p4.w, vr3, facc[l]);
        }
    }

    // ---- epilogue: deferred softmax normalization + coalesced store ----
#pragma unroll
    for (int l = 0; l < 7; ++l)
        out[qbase + l * 512 + lane] = facc[l] * rdenom[l];
}

extern "C" void kernel_launch(void* const* d_in, const int* in_sizes, int n_in,
                              void* d_out, int out_size, void* d_ws, size_t ws_size,
                              hipStream_t stream) {
    const float* q    = (const float*)d_in[0];
    const float* k    = (const float*)d_in[1];
    const float* v    = (const float*)d_in[2];
    const float* mask = (const float*)d_in[3];
    float* out        = (float*)d_out;

    const int B = in_sizes[0] / (7 * 8 * 64);        // 3200
    const int nstations = in_sizes[3] / (7 * 56);    // 50

    fullattn_kernel<<<dim3(B * 8), dim3(64), 0, stream>>>(q, k, v, mask, out, nstations);
}